// Round 1
// baseline (2558.323 us; speedup 1.0000x reference)
//
#include <hip/hip_runtime.h>
#include <math.h>

#define DDIM 64

__global__ void deg_kernel(const int* __restrict__ erow, const int* __restrict__ ecol,
                           const float* __restrict__ evals,
                           float* __restrict__ deg_r, float* __restrict__ deg_c, int E) {
    int e = blockIdx.x * blockDim.x + threadIdx.x;
    if (e < E) {
        float v = evals[e];
        atomicAdd(&deg_r[erow[e]], v);
        atomicAdd(&deg_c[ecol[e]], v);
    }
}

__global__ void inv_kernel(float* __restrict__ deg, int n) {
    int i = blockIdx.x * blockDim.x + threadIdx.x;
    if (i < n) deg[i] = 1.0f / (sqrtf(deg[i]) + 1e-8f);
}

// one wave per edge, lane = feature dim
__global__ void spmm_kernel(const int* __restrict__ erow, const int* __restrict__ ecol,
                            const float* __restrict__ evals,
                            const float* __restrict__ inv_r, const float* __restrict__ inv_c,
                            const float* __restrict__ feat, float* __restrict__ outf, int E) {
    long gid = (long)blockIdx.x * blockDim.x + threadIdx.x;
    int e = (int)(gid >> 6);
    int lane = threadIdx.x & 63;
    if (e < E) {
        int r = erow[e], c = ecol[e];
        float v = evals[e] * inv_r[r] * inv_c[c];
        atomicAdd(&outf[(long)r * DDIM + lane], v * feat[(long)c * DDIM + lane]);
    }
}

// one wave per node row: acc += feat / max(||feat||, 1e-12)
__global__ void norm_acc_kernel(const float* __restrict__ feat, float* __restrict__ acc, int N) {
    long gid = (long)blockIdx.x * blockDim.x + threadIdx.x;
    int i = (int)(gid >> 6);
    int lane = threadIdx.x & 63;
    if (i < N) {
        float f = feat[(long)i * DDIM + lane];
        float ss = f * f;
        #pragma unroll
        for (int off = 1; off < 64; off <<= 1) ss += __shfl_xor(ss, off);
        float s = 1.0f / fmaxf(sqrtf(ss), 1e-12f);
        acc[(long)i * DDIM + lane] += f * s;
    }
}

// one wave per sample: two dot products + stable softplus(-x)
__global__ void loss_terms_kernel(const float* __restrict__ acc,
                                  const int* __restrict__ a_id, const int* __restrict__ p_id,
                                  const int* __restrict__ n_id,
                                  float* __restrict__ terms, int B) {
    long gid = (long)blockIdx.x * blockDim.x + threadIdx.x;
    int b = (int)(gid >> 6);
    int lane = threadIdx.x & 63;
    if (b < B) {
        int ia = a_id[b], ip = p_id[b], in2 = n_id[b];
        float a = acc[(long)ia * DDIM + lane];
        float p = acc[(long)ip * DDIM + lane];
        float n = acc[(long)in2 * DDIM + lane];
        float dp = a * p, dn = a * n;
        #pragma unroll
        for (int off = 1; off < 64; off <<= 1) { dp += __shfl_xor(dp, off); dn += __shfl_xor(dn, off); }
        if (lane == 0) {
            // node_rep = acc/4  ->  preds scale by 1/16
            float x = (dp - dn) * 0.0625f;
            // -log_sigmoid(x) = softplus(-x), numerically stable
            terms[b] = fmaxf(-x, 0.0f) + log1pf(expf(-fabsf(x)));
        }
    }
}

__global__ void reduce_kernel(const float* __restrict__ terms, float* __restrict__ out, int B) {
    __shared__ float sm[256];
    float s = 0.0f;
    for (int i = threadIdx.x; i < B; i += 256) s += terms[i];
    sm[threadIdx.x] = s;
    __syncthreads();
    for (int stride = 128; stride > 0; stride >>= 1) {
        if (threadIdx.x < stride) sm[threadIdx.x] += sm[threadIdx.x + stride];
        __syncthreads();
    }
    if (threadIdx.x == 0) out[0] = sm[0] / (float)B;
}

extern "C" void kernel_launch(void* const* d_in, const int* in_sizes, int n_in,
                              void* d_out, int out_size, void* d_ws, size_t ws_size,
                              hipStream_t stream) {
    const float* nf    = (const float*)d_in[0];
    const int*   erow  = (const int*)d_in[1];
    const int*   ecol  = (const int*)d_in[2];
    const float* evals = (const float*)d_in[3];
    const int*   a_id  = (const int*)d_in[4];
    const int*   p_id  = (const int*)d_in[5];
    const int*   n_id  = (const int*)d_in[6];

    int N = in_sizes[0] / DDIM;
    int E = in_sizes[1];
    int B = in_sizes[4];

    float* ws    = (float*)d_ws;
    float* deg_r = ws;                          // N
    float* deg_c = deg_r + N;                   // N
    float* f0    = deg_c + N;                   // N*D
    float* f1    = f0 + (size_t)N * DDIM;       // N*D
    float* acc   = f1 + (size_t)N * DDIM;       // N*D
    float* terms = acc + (size_t)N * DDIM;      // B

    // degrees + inverse sqrt norms
    hipMemsetAsync(deg_r, 0, (size_t)2 * N * sizeof(float), stream);
    deg_kernel<<<(E + 255) / 256, 256, 0, stream>>>(erow, ecol, evals, deg_r, deg_c, E);
    inv_kernel<<<(2 * N + 255) / 256, 256, 0, stream>>>(deg_r, 2 * N);

    // acc = node_features (layer-0 term)
    hipMemcpyAsync(acc, nf, (size_t)N * DDIM * sizeof(float), hipMemcpyDeviceToDevice, stream);

    const float* cur = nf;
    float* bufs[2] = {f0, f1};
    for (int l = 0; l < 3; l++) {
        float* nxt = bufs[l & 1];
        hipMemsetAsync(nxt, 0, (size_t)N * DDIM * sizeof(float), stream);
        long threads = (long)E * 64;
        spmm_kernel<<<(unsigned)((threads + 255) / 256), 256, 0, stream>>>(
            erow, ecol, evals, deg_r, deg_c, cur, nxt, E);
        norm_acc_kernel<<<(unsigned)(((long)N * 64 + 255) / 256), 256, 0, stream>>>(nxt, acc, N);
        cur = nxt;
    }

    loss_terms_kernel<<<(unsigned)(((long)B * 64 + 255) / 256), 256, 0, stream>>>(
        acc, a_id, p_id, n_id, terms, B);
    reduce_kernel<<<1, 256, 0, stream>>>(terms, (float*)d_out, B);
}

// Round 2
// 1296.008 us; speedup vs baseline: 1.9740x; 1.9740x over previous
//
#include <hip/hip_runtime.h>
#include <math.h>

#define DDIM 64

// ---- degree + histogram (fused) ----
__global__ void deg_hist_kernel(const int* __restrict__ erow, const int* __restrict__ ecol,
                                const float* __restrict__ evals,
                                float* __restrict__ deg_r, float* __restrict__ deg_c,
                                int* __restrict__ cnt, int E) {
    int e = blockIdx.x * blockDim.x + threadIdx.x;
    if (e < E) {
        float v = evals[e];
        int r = erow[e];
        atomicAdd(&deg_r[r], v);
        atomicAdd(&deg_c[ecol[e]], v);
        atomicAdd(&cnt[r], 1);
    }
}

__global__ void inv_kernel(float* __restrict__ deg, int n) {
    int i = blockIdx.x * blockDim.x + threadIdx.x;
    if (i < n) deg[i] = 1.0f / (sqrtf(deg[i]) + 1e-8f);
}

// ---- exclusive scan over cnt -> rowptr (3-phase) ----
__global__ void scan_chunks(const int* __restrict__ cnt, int* __restrict__ rowptr,
                            int* __restrict__ partials, int N) {
    __shared__ int sm[1024];
    int t = threadIdx.x;
    int i = blockIdx.x * 1024 + t;
    int v = (i < N) ? cnt[i] : 0;
    sm[t] = v;
    __syncthreads();
    for (int off = 1; off < 1024; off <<= 1) {
        int add = (t >= off) ? sm[t - off] : 0;
        __syncthreads();
        sm[t] += add;
        __syncthreads();
    }
    if (i < N) rowptr[i] = sm[t] - v;          // exclusive within chunk
    if (t == 1023) partials[blockIdx.x] = sm[1023];
}

__global__ void scan_partials(int* __restrict__ partials, int P) {
    __shared__ int sm[1024];
    int t = threadIdx.x;
    int v = (t < P) ? partials[t] : 0;
    sm[t] = v;
    __syncthreads();
    for (int off = 1; off < 1024; off <<= 1) {
        int add = (t >= off) ? sm[t - off] : 0;
        __syncthreads();
        sm[t] += add;
        __syncthreads();
    }
    if (t < P) partials[t] = sm[t] - v;        // exclusive
}

__global__ void add_offsets(int* __restrict__ rowptr, const int* __restrict__ partials,
                            int N, int E) {
    int i = blockIdx.x * blockDim.x + threadIdx.x;
    if (i < N) rowptr[i] += partials[i >> 10];
    if (i == N) rowptr[N] = E;
}

// ---- scatter edges into CSR; weight = val * inv_c[col] (layer-invariant) ----
__global__ void scatter_kernel(const int* __restrict__ erow, const int* __restrict__ ecol,
                               const float* __restrict__ evals, const float* __restrict__ inv_c,
                               const int* __restrict__ rowptr, int* __restrict__ fill,
                               int2* __restrict__ cw, int E) {
    int e = blockIdx.x * blockDim.x + threadIdx.x;
    if (e < E) {
        int r = erow[e], c = ecol[e];
        int pos = rowptr[r] + atomicAdd(&fill[r], 1);
        float w = evals[e] * inv_c[c];
        int2 packed;
        packed.x = c;
        packed.y = __float_as_int(w);
        cw[pos] = packed;
    }
}

// ---- gather SpMM, one wave per row, fused L2-normalize + acc update ----
__global__ void spmm_csr_kernel(const int* __restrict__ rowptr, const int2* __restrict__ cw,
                                const float* __restrict__ inv_r,
                                const float* __restrict__ feat, float* __restrict__ outf,
                                float* __restrict__ acc, int N) {
    long gid = (long)blockIdx.x * blockDim.x + threadIdx.x;
    int i = (int)(gid >> 6);
    int lane = threadIdx.x & 63;
    if (i >= N) return;
    int s = rowptr[i], e = rowptr[i + 1];
    float a = 0.0f;
    for (int base = s; base < e; base += 64) {
        int nk = e - base;
        if (nk > 64) nk = 64;
        int c = 0;
        float w = 0.0f;
        if (base + lane < e) {
            int2 p = cw[base + lane];
            c = p.x;
            w = __int_as_float(p.y);
        }
        for (int j = 0; j < nk; j++) {
            int cj = __shfl(c, j);
            float wj = __shfl(w, j);
            a += wj * feat[(long)cj * DDIM + lane];
        }
    }
    a *= inv_r[i];
    outf[(long)i * DDIM + lane] = a;
    // L2 row norm
    float ss = a * a;
    #pragma unroll
    for (int off = 1; off < 64; off <<= 1) ss += __shfl_xor(ss, off);
    float s2 = 1.0f / fmaxf(sqrtf(ss), 1e-12f);
    acc[(long)i * DDIM + lane] += a * s2;
}

// ---- BPR loss ----
__global__ void loss_terms_kernel(const float* __restrict__ acc,
                                  const int* __restrict__ a_id, const int* __restrict__ p_id,
                                  const int* __restrict__ n_id,
                                  float* __restrict__ terms, int B) {
    long gid = (long)blockIdx.x * blockDim.x + threadIdx.x;
    int b = (int)(gid >> 6);
    int lane = threadIdx.x & 63;
    if (b < B) {
        int ia = a_id[b], ip = p_id[b], in2 = n_id[b];
        float a = acc[(long)ia * DDIM + lane];
        float p = acc[(long)ip * DDIM + lane];
        float n = acc[(long)in2 * DDIM + lane];
        float dp = a * p, dn = a * n;
        #pragma unroll
        for (int off = 1; off < 64; off <<= 1) { dp += __shfl_xor(dp, off); dn += __shfl_xor(dn, off); }
        if (lane == 0) {
            float x = (dp - dn) * 0.0625f;   // node_rep = acc/4 -> preds scale 1/16
            terms[b] = fmaxf(-x, 0.0f) + log1pf(expf(-fabsf(x)));
        }
    }
}

__global__ void reduce_kernel(const float* __restrict__ terms, float* __restrict__ out, int B) {
    __shared__ float sm[256];
    float s = 0.0f;
    for (int i = threadIdx.x; i < B; i += 256) s += terms[i];
    sm[threadIdx.x] = s;
    __syncthreads();
    for (int stride = 128; stride > 0; stride >>= 1) {
        if (threadIdx.x < stride) sm[threadIdx.x] += sm[threadIdx.x + stride];
        __syncthreads();
    }
    if (threadIdx.x == 0) out[0] = sm[0] / (float)B;
}

extern "C" void kernel_launch(void* const* d_in, const int* in_sizes, int n_in,
                              void* d_out, int out_size, void* d_ws, size_t ws_size,
                              hipStream_t stream) {
    const float* nf    = (const float*)d_in[0];
    const int*   erow  = (const int*)d_in[1];
    const int*   ecol  = (const int*)d_in[2];
    const float* evals = (const float*)d_in[3];
    const int*   a_id  = (const int*)d_in[4];
    const int*   p_id  = (const int*)d_in[5];
    const int*   n_id  = (const int*)d_in[6];

    int N = in_sizes[0] / DDIM;
    int E = in_sizes[1];
    int B = in_sizes[4];

    char* w = (char*)d_ws;
    float* deg_r   = (float*)w;                 w += (size_t)N * 4;
    float* deg_c   = (float*)w;                 w += (size_t)N * 4;
    int*   cnt     = (int*)w;                   w += (size_t)N * 4;
    int*   fill    = (int*)w;                   w += (size_t)N * 4;
    int*   rowptr  = (int*)w;                   w += (size_t)(N + 1) * 4;
    int*   partials= (int*)w;                   w += (size_t)1024 * 4;
    int2*  cw      = (int2*)w;                  w += (size_t)E * 8;
    float* f0      = (float*)w;                 w += (size_t)N * DDIM * 4;
    float* f1      = (float*)w;                 w += (size_t)N * DDIM * 4;
    float* acc     = (float*)w;                 w += (size_t)N * DDIM * 4;
    float* terms   = (float*)w;                 w += (size_t)B * 4;

    // zero degree/hist/fill
    hipMemsetAsync(deg_r, 0, (size_t)2 * N * sizeof(float), stream);
    hipMemsetAsync(cnt, 0, (size_t)2 * N * sizeof(int), stream);   // cnt + fill contiguous

    deg_hist_kernel<<<(E + 255) / 256, 256, 0, stream>>>(erow, ecol, evals, deg_r, deg_c, cnt, E);
    inv_kernel<<<(2 * N + 255) / 256, 256, 0, stream>>>(deg_r, 2 * N);

    // scan cnt -> rowptr
    int nChunks = (N + 1023) / 1024;
    scan_chunks<<<nChunks, 1024, 0, stream>>>(cnt, rowptr, partials, N);
    scan_partials<<<1, 1024, 0, stream>>>(partials, nChunks);
    add_offsets<<<(N + 1 + 255) / 256, 256, 0, stream>>>(rowptr, partials, N, E);

    // CSR scatter with fused inv_c weight
    scatter_kernel<<<(E + 255) / 256, 256, 0, stream>>>(erow, ecol, evals, deg_c, rowptr, fill, cw, E);

    // acc = node_features (layer-0 term)
    hipMemcpyAsync(acc, nf, (size_t)N * DDIM * sizeof(float), hipMemcpyDeviceToDevice, stream);

    const float* cur = nf;
    float* bufs[2] = {f0, f1};
    unsigned spmmGrid = (unsigned)(((long)N * 64 + 255) / 256);
    for (int l = 0; l < 3; l++) {
        float* nxt = bufs[l & 1];
        spmm_csr_kernel<<<spmmGrid, 256, 0, stream>>>(rowptr, cw, deg_r, cur, nxt, acc, N);
        cur = nxt;
    }

    loss_terms_kernel<<<(unsigned)(((long)B * 64 + 255) / 256), 256, 0, stream>>>(
        acc, a_id, p_id, n_id, terms, B);
    reduce_kernel<<<1, 256, 0, stream>>>(terms, (float*)d_out, B);
}